// Round 7
// baseline (237.433 us; speedup 1.0000x reference)
//
#include <hip/hip_runtime.h>
#include <hip/hip_bf16.h>

// Problem constants
#define B_SZ   64
#define L_SZ   52
#define DMODEL 4096
#define H_SZ   32
#define C_SZ   128   // NEW_C = DMODEL/H
#define DK     128   // D_K == D_V

// Output GEMM dims: (B*L) x DMODEL = 3328 x 4096, K = 4096
#define GM 3328
#define GN 4096
#define GK 4096

typedef __bf16 bf16x8 __attribute__((ext_vector_type(8)));
typedef float  f32x4  __attribute__((ext_vector_type(4)));

__device__ __forceinline__ void gload_lds16(const void* g, void* l) {
  __builtin_amdgcn_global_load_lds(
      (__attribute__((address_space(1))) void*)(void*)g,
      (__attribute__((address_space(3))) void*)l, 16, 0, 0);
}

// ---------------------------------------------------------------------------
// Kernel 1a: Wo (4096x4096 fp32 [m][n]) -> WoT (4096x4096 bf16 [n][m])
// ---------------------------------------------------------------------------
__global__ __launch_bounds__(256) void wo_transpose_kernel(
    const float* __restrict__ Wo, __hip_bfloat16* __restrict__ WoT) {
  __shared__ float tile[64][65];
  const int nt = blockIdx.x, mt = blockIdx.y;
  const int t = threadIdx.x;
  const int r  = t >> 4;
  const int c4 = (t & 15) << 2;
#pragma unroll
  for (int p = 0; p < 4; ++p) {
    const int rr = r + p * 16;
    const float4 v = *(const float4*)(Wo + (size_t)(mt * 64 + rr) * 4096 + nt * 64 + c4);
    tile[rr][c4 + 0] = v.x; tile[rr][c4 + 1] = v.y;
    tile[rr][c4 + 2] = v.z; tile[rr][c4 + 3] = v.w;
  }
  __syncthreads();
#pragma unroll
  for (int p = 0; p < 4; ++p) {
    const int rr = r + p * 16;
    union { __hip_bfloat16 h[4]; ushort4 u; } o4;
#pragma unroll
    for (int e = 0; e < 4; ++e) o4.h[e] = __float2bfloat16(tile[c4 + e][rr]);
    *(ushort4*)(WoT + (size_t)(nt * 64 + rr) * 4096 + mt * 64 + c4) = o4.u;
  }
}

// ---------------------------------------------------------------------------
// Kernel 1b: Wq/Wk/Wv [h][c][k] fp32 -> [h][k][c] bf16   (batched 128x128 T)
// ---------------------------------------------------------------------------
__global__ __launch_bounds__(256) void w3_transpose_kernel(
    const float* __restrict__ Wq, const float* __restrict__ Wk,
    const float* __restrict__ Wv, __hip_bfloat16* __restrict__ WqT,
    __hip_bfloat16* __restrict__ WkT, __hip_bfloat16* __restrict__ WvT) {
  __shared__ float tile[64][65];
  const int bz = blockIdx.z;
  const float* in = (bz < 32 ? Wq : (bz < 64 ? Wk : Wv)) + (size_t)(bz & 31) * 16384;
  __hip_bfloat16* out = (bz < 32 ? WqT : (bz < 64 ? WkT : WvT)) + (size_t)(bz & 31) * 16384;
  const int nt = blockIdx.x, mt = blockIdx.y;  // 0..1
  const int t = threadIdx.x;
  const int r  = t >> 4;
  const int c4 = (t & 15) << 2;
#pragma unroll
  for (int p = 0; p < 4; ++p) {
    const int rr = r + p * 16;
    const float4 v = *(const float4*)(in + (size_t)(mt * 64 + rr) * 128 + nt * 64 + c4);
    tile[rr][c4 + 0] = v.x; tile[rr][c4 + 1] = v.y;
    tile[rr][c4 + 2] = v.z; tile[rr][c4 + 3] = v.w;
  }
  __syncthreads();
#pragma unroll
  for (int p = 0; p < 4; ++p) {
    const int rr = r + p * 16;
    union { __hip_bfloat16 h[4]; ushort4 u; } o4;
#pragma unroll
    for (int e = 0; e < 4; ++e) o4.h[e] = __float2bfloat16(tile[c4 + e][rr]);
    *(ushort4*)(out + (size_t)(nt * 64 + rr) * 128 + mt * 64 + c4) = o4.u;
  }
}

// ---------------------------------------------------------------------------
// Kernel 2: per-(b,h) MFMA attention, barrier-lean version.
// 256 threads = 4 waves; grid (H, B) = 2048 blocks; 2 blocks/CU.
// LDS (dedicated regions, 70656 B):
//   q_sh [    0,17408)  64x136 bf16      (p_sh overlays after softmax)
//   k_sh [17408,34816)  64x136 bf16
//   vT   [34816,53248)  128x72 bf16 (transposed, pad-zeroed)
//   s_sh [53248,70656)  64x68  f32
// Phases: {proj q,k,v} -> B1 -> QK^T -> B2 -> softmax -> B3 -> PV. 3 barriers.
// Projection A-fragments are read DIRECTLY from global fp32 (no LDS staging
// pass): rows >= 52 clamped to 51 (garbage is provably masked downstream).
// ---------------------------------------------------------------------------
template <bool TRANSPOSED>
__device__ __forceinline__ void proj_g(
    const float* __restrict__ X, const __hip_bfloat16* __restrict__ WT,
    const float* __restrict__ bias, __hip_bfloat16* __restrict__ out,
    int n0, int r16, int kq) {
  f32x4 acc[4][2] = {};
  bf16x8 bfrag[2][4];
#pragma unroll
  for (int nt = 0; nt < 2; ++nt)
#pragma unroll
    for (int kk = 0; kk < 4; ++kk)
      bfrag[nt][kk] = *(const bf16x8*)(WT + (n0 + nt * 16 + r16) * 128 + kk * 32 + kq * 8);
#pragma unroll
  for (int kk = 0; kk < 4; ++kk) {
    bf16x8 a[4];
#pragma unroll
    for (int mt = 0; mt < 4; ++mt) {
      const int row = mt * 16 + r16;
      const int rowc = row < 52 ? row : 51;       // clamp: pad rows masked later
      const float4* xp = (const float4*)(X + rowc * 128 + kk * 32 + kq * 8);
      const float4 x0 = xp[0], x1 = xp[1];
      union { __hip_bfloat16 h[8]; bf16x8 v; } cv;
      cv.h[0] = __float2bfloat16(x0.x); cv.h[1] = __float2bfloat16(x0.y);
      cv.h[2] = __float2bfloat16(x0.z); cv.h[3] = __float2bfloat16(x0.w);
      cv.h[4] = __float2bfloat16(x1.x); cv.h[5] = __float2bfloat16(x1.y);
      cv.h[6] = __float2bfloat16(x1.z); cv.h[7] = __float2bfloat16(x1.w);
      a[mt] = cv.v;
    }
#pragma unroll
    for (int mt = 0; mt < 4; ++mt)
#pragma unroll
      for (int nt = 0; nt < 2; ++nt)
        acc[mt][nt] = __builtin_amdgcn_mfma_f32_16x16x32_bf16(a[mt], bfrag[nt][kk], acc[mt][nt], 0, 0, 0);
  }
#pragma unroll
  for (int nt = 0; nt < 2; ++nt) {
    const int col = n0 + nt * 16 + r16;
    const float bv = bias[col];
#pragma unroll
    for (int mt = 0; mt < 4; ++mt) {
      const int m0 = mt * 16 + kq * 4;
      if (!TRANSPOSED) {
#pragma unroll
        for (int i = 0; i < 4; ++i)
          out[(m0 + i) * 136 + col] = __float2bfloat16(acc[mt][nt][i] + bv);
      } else {
        union { __hip_bfloat16 h[4]; ushort4 u; } o4;
        if (m0 < 52) {
#pragma unroll
          for (int i = 0; i < 4; ++i) o4.h[i] = __float2bfloat16(acc[mt][nt][i] + bv);
        } else {
          o4.u = make_ushort4(0, 0, 0, 0);   // pad keys: v rows 52..63 = 0
        }
        *(ushort4*)(out + col * 72 + m0) = o4.u;
      }
    }
  }
}

__global__ __launch_bounds__(256, 2) void attn_kernel(
    const float* __restrict__ Qin, const float* __restrict__ Kin,
    const float* __restrict__ Vin,
    const __hip_bfloat16* __restrict__ WqT, const float* __restrict__ bq,
    const __hip_bfloat16* __restrict__ WkT, const float* __restrict__ bk,
    const __hip_bfloat16* __restrict__ WvT, const float* __restrict__ bv,
    __hip_bfloat16* __restrict__ Oc) {
  __shared__ __align__(16) char lds[70656];
  __hip_bfloat16* q_sh = (__hip_bfloat16*)(lds);
  __hip_bfloat16* k_sh = (__hip_bfloat16*)(lds + 17408);
  __hip_bfloat16* vT   = (__hip_bfloat16*)(lds + 34816);
  float*          s_sh = (float*)(lds + 53248);
  __hip_bfloat16* p_sh = (__hip_bfloat16*)(lds);        // overlays dead q_sh

  const int h = blockIdx.x, bb = blockIdx.y;
  const int t = threadIdx.x;
  const int w = t >> 6, lane = t & 63;
  const int r16 = lane & 15, kq = lane >> 4;
  const size_t xoff = (size_t)bb * (L_SZ * DMODEL) + (size_t)h * (L_SZ * C_SZ);
  const int n0 = w * 32;

  // ---- phase 1: q/k/v projections straight from global (no staging) ----
  proj_g<false>(Qin + xoff, WqT + (size_t)h * 16384, bq + h * 128, q_sh, n0, r16, kq);
  proj_g<false>(Kin + xoff, WkT + (size_t)h * 16384, bk + h * 128, k_sh, n0, r16, kq);
  proj_g<true >(Vin + xoff, WvT + (size_t)h * 16384, bv + h * 128, vT,   n0, r16, kq);
  __syncthreads();   // B1

  // ---- phase 2: QK^T -> s_sh, scaled ----
  {
    const int nq = w * 16;
    f32x4 sacc[4] = {};
#pragma unroll
    for (int kk = 0; kk < 4; ++kk) {
      const bf16x8 bf_ = *(const bf16x8*)(k_sh + (nq + r16) * 136 + kk * 32 + kq * 8);
#pragma unroll
      for (int mt = 0; mt < 4; ++mt) {
        const bf16x8 a = *(const bf16x8*)(q_sh + (mt * 16 + r16) * 136 + kk * 32 + kq * 8);
        sacc[mt] = __builtin_amdgcn_mfma_f32_16x16x32_bf16(a, bf_, sacc[mt], 0, 0, 0);
      }
    }
    const float scale = 0.08838834764831845f;  // 1/sqrt(128)
#pragma unroll
    for (int mt = 0; mt < 4; ++mt)
#pragma unroll
      for (int i = 0; i < 4; ++i)
        s_sh[(mt * 16 + kq * 4 + i) * 68 + nq + r16] = sacc[mt][i] * scale;
  }
  __syncthreads();   // B2

  // ---- phase 3: masked softmax: s_sh -> p_sh (overlays q_sh) ----
  {
    const int r = t >> 2, qd = t & 3;   // 4 lanes per row, 16 cols each
    if (r < 52) {
      float v[16];
      float mx = -3e38f;
#pragma unroll
      for (int j4 = 0; j4 < 4; ++j4) {
        const f32x4 s4 = *(const f32x4*)(s_sh + r * 68 + qd * 16 + j4 * 4);
#pragma unroll
        for (int e = 0; e < 4; ++e) {
          const int col = qd * 16 + j4 * 4 + e;
          const float val = (col <= r) ? s4[e] : -3e38f;
          v[j4 * 4 + e] = val;
          mx = fmaxf(mx, val);
        }
      }
      mx = fmaxf(mx, __shfl_xor(mx, 1));
      mx = fmaxf(mx, __shfl_xor(mx, 2));
      float ex[16];
      float sum = 0.f;
#pragma unroll
      for (int j = 0; j < 16; ++j) {
        const int col = qd * 16 + j;
        const float e = (col <= r) ? __expf(v[j] - mx) : 0.f;
        ex[j] = e; sum += e;
      }
      sum += __shfl_xor(sum, 1);
      sum += __shfl_xor(sum, 2);
      const float inv = 1.0f / sum;
      union { __hip_bfloat16 h[8]; uint4 q; } p0, p1;
#pragma unroll
      for (int j = 0; j < 8; ++j) {
        p0.h[j] = __float2bfloat16(ex[j] * inv);
        p1.h[j] = __float2bfloat16(ex[8 + j] * inv);
      }
      *(uint4*)(p_sh + r * 72 + qd * 16)     = p0.q;
      *(uint4*)(p_sh + r * 72 + qd * 16 + 8) = p1.q;
    } else {
      *(uint4*)(p_sh + r * 72 + qd * 16)     = make_uint4(0, 0, 0, 0);
      *(uint4*)(p_sh + r * 72 + qd * 16 + 8) = make_uint4(0, 0, 0, 0);
    }
  }
  __syncthreads();   // B3

  // ---- phase 4: PV: p_sh(64x64) @ v(64x128) -> Oc bf16 ----
  {
    f32x4 oacc[4][2] = {};
#pragma unroll
    for (int kk = 0; kk < 2; ++kk) {
      bf16x8 bfr[2];
#pragma unroll
      for (int nt = 0; nt < 2; ++nt)
        bfr[nt] = *(const bf16x8*)(vT + (n0 + nt * 16 + r16) * 72 + kk * 32 + kq * 8);
#pragma unroll
      for (int mt = 0; mt < 4; ++mt) {
        const bf16x8 a = *(const bf16x8*)(p_sh + (mt * 16 + r16) * 72 + kk * 32 + kq * 8);
#pragma unroll
        for (int nt = 0; nt < 2; ++nt)
          oacc[mt][nt] = __builtin_amdgcn_mfma_f32_16x16x32_bf16(a, bfr[nt], oacc[mt][nt], 0, 0, 0);
      }
    }
    const size_t obase = (size_t)bb * 52 * 4096 + (size_t)h * 128;
#pragma unroll
    for (int nt = 0; nt < 2; ++nt) {
      const int col = n0 + nt * 16 + r16;
#pragma unroll
      for (int mt = 0; mt < 4; ++mt) {
        const int row0 = mt * 16 + kq * 4;
#pragma unroll
        for (int i = 0; i < 4; ++i) {
          const int row = row0 + i;
          if (row < 52)
            Oc[obase + (size_t)row * 4096 + col] = __float2bfloat16(oacc[mt][nt][i]);
        }
      }
    }
  }
}

// ---------------------------------------------------------------------------
// Kernel 3: C = Oc @ WoT^T + bo — m201-style 4-phase/K-tile schedule (as R6).
// ---------------------------------------------------------------------------
#define STAGE(GBASE, REGOFF, KT, KS, WB) do {                                  \
    const __hip_bfloat16* s_ = (GBASE) + (size_t)(KT) * 64 + (KS) * 32;        \
    char* d_ = (WB) + (REGOFF) + ((KS) ? 16384 : 0) + t * 16;                  \
    gload_lds16(s_, d_);                                                       \
    gload_lds16(s_ + (size_t)128 * GK, d_ + 8192);                             \
  } while (0)

#define MFMA16(MQ, BF)                                                         \
  __builtin_amdgcn_sched_barrier(0);                                           \
  __builtin_amdgcn_s_setprio(1);                                               \
  _Pragma("unroll")                                                            \
  for (int mf = 0; mf < 4; ++mf)                                               \
    _Pragma("unroll")                                                          \
    for (int nf = 0; nf < 4; ++nf)                                             \
      acc[(MQ) * 4 + mf][nf] = __builtin_amdgcn_mfma_f32_16x16x32_bf16(        \
          af[mf], BF[nf], acc[(MQ) * 4 + mf][nf], 0, 0, 0);                    \
  __builtin_amdgcn_s_setprio(0)

#define READ_AF(KS, MQ)                                                        \
  _Pragma("unroll")                                                            \
  for (int mf = 0; mf < 4; ++mf)                                               \
    af[mf] = *(const bf16x8*)(rb + (KS) * 16384 + (MQ) * 4096 + aB0 + mf * 1024)

#define READ_BF(BF, KS)                                                        \
  _Pragma("unroll")                                                            \
  for (int nf = 0; nf < 4; ++nf)                                               \
    BF[nf] = *(const bf16x8*)(rb + 32768 + (KS) * 16384 + bB0 + nf * 1024)

__global__ __launch_bounds__(512, 2) void out_gemm_kernel(
    const __hip_bfloat16* __restrict__ A, const __hip_bfloat16* __restrict__ Bt,
    const float* __restrict__ bias, float* __restrict__ C) {
  __shared__ __align__(16) char lds[131072];   // 2 bufs x 64 KB

  int bid = blockIdx.x;
  bid = (bid & 7) * 26 + (bid >> 3);     // XCD swizzle, 208 % 8 == 0 (bijective)
  const int tm = bid >> 4;               // 0..12
  const int tn = bid & 15;               // 0..15

  const int t = threadIdx.x;
  const int w = t >> 6, lane = t & 63;
  const int wm = w >> 2, wn = w & 3;     // 2M x 4N waves; wave tile 128x64
  const int r16 = lane & 15, kq = lane >> 4;

  const int srow = t >> 2;
  const int sgslot = (t & 3) ^ ((srow >> 1) & 3);
  const __hip_bfloat16* gA0 = A  + (size_t)(tm * 256 + srow) * GK + sgslot * 8;
  const __hip_bfloat16* gB0 = Bt + (size_t)(tn * 256 + srow) * GK + sgslot * 8;

  const int slotr = kq ^ ((r16 >> 1) & 3);
  const int aB0 = (wm * 128 + r16) * 64 + slotr * 16;
  const int bB0 = (wn * 64 + r16) * 64 + slotr * 16;

  f32x4 acc[8][4] = {};
  bf16x8 bf0[4], bf1[4];

  STAGE(gA0, 0,     0, 0, lds);
  STAGE(gA0, 0,     0, 1, lds);
  STAGE(gB0, 32768, 0, 0, lds);
  STAGE(gB0, 32768, 0, 1, lds);
  STAGE(gB0, 32768, 1, 0, lds + 65536);
  STAGE(gA0, 0,     1, 0, lds + 65536);
  STAGE(gB0, 32768, 1, 1, lds + 65536);
  asm volatile("s_waitcnt vmcnt(6)" ::: "memory");   // T0's 8 loads landed
  __builtin_amdgcn_s_barrier();

#pragma unroll 1
  for (int kt = 0; kt < 64; ++kt) {
    char* rb = lds + ((kt & 1) << 16);
    char* ob = lds + (((kt + 1) & 1) << 16);
    const int s1 = kt + 1 < 64 ? kt + 1 : 63;
    const int s2 = kt + 2 < 64 ? kt + 2 : 63;

    {
      bf16x8 af[4];
      READ_AF(0, 0);
      READ_BF(bf0, 0);
      STAGE(gA0, 0, s1, 1, ob);
      __builtin_amdgcn_s_barrier();
      asm volatile("s_waitcnt lgkmcnt(0)" ::: "memory");
      MFMA16(0, bf0);
      __builtin_amdgcn_s_barrier();
    }
    {
      bf16x8 af[4];
      READ_AF(0, 1);
      STAGE(gB0, 32768, s2, 0, rb);
      __builtin_amdgcn_s_barrier();
      asm volatile("s_waitcnt lgkmcnt(0)" ::: "memory");
      MFMA16(1, bf0);
      __builtin_amdgcn_s_barrier();
    }
    {
      bf16x8 af[4];
      READ_AF(1, 0);
      READ_BF(bf1, 1);
      STAGE(gA0, 0, s2, 0, rb);
      __builtin_amdgcn_s_barrier();
      asm volatile("s_waitcnt lgkmcnt(0)" ::: "memory");
      MFMA16(0, bf1);
      __builtin_amdgcn_s_barrier();
    }
    {
      bf16x8 af[4];
      READ_AF(1, 1);
      STAGE(gB0, 32768, s2, 1, rb);
      __builtin_amdgcn_s_barrier();
      asm volatile("s_waitcnt lgkmcnt(0)" ::: "memory");
      MFMA16(1, bf1);
      asm volatile("s_waitcnt vmcnt(6)" ::: "memory");  // T+1 fully landed
      __builtin_amdgcn_s_barrier();
    }
  }
  asm volatile("s_waitcnt vmcnt(0) lgkmcnt(0)" ::: "memory");

  const int row0 = tm * 256 + wm * 128 + kq * 4;
  const int col0 = tn * 256 + wn * 64 + r16;
#pragma unroll
  for (int nf = 0; nf < 4; ++nf) {
    const int col = col0 + nf * 16;
    const float bv = bias[col];
#pragma unroll
    for (int mf = 0; mf < 8; ++mf) {
      const int row = row0 + mf * 16;
#pragma unroll
      for (int i = 0; i < 4; ++i)
        C[(size_t)(row + i) * GN + col] = acc[mf][nf][i] + bv;
    }
  }
}

// ---------------------------------------------------------------------------
extern "C" void kernel_launch(void* const* d_in, const int* in_sizes, int n_in,
                              void* d_out, int out_size, void* d_ws, size_t ws_size,
                              hipStream_t stream) {
  const float* Q  = (const float*)d_in[0];
  const float* K  = (const float*)d_in[1];
  const float* V  = (const float*)d_in[2];
  const float* Wq = (const float*)d_in[3];
  const float* bq = (const float*)d_in[4];
  const float* Wk = (const float*)d_in[5];
  const float* bk = (const float*)d_in[6];
  const float* Wv = (const float*)d_in[7];
  const float* bv = (const float*)d_in[8];
  const float* Wo = (const float*)d_in[9];
  const float* bo = (const float*)d_in[10];
  float* out = (float*)d_out;

  char* wsb = (char*)d_ws;
  __hip_bfloat16* WoT = (__hip_bfloat16*)wsb;
  __hip_bfloat16* Oc  = (__hip_bfloat16*)(wsb + (size_t)GN * GK * 2);
  __hip_bfloat16* WqT = (__hip_bfloat16*)(wsb + (size_t)GN * GK * 2 + (size_t)GM * GN * 2);
  __hip_bfloat16* WkT = WqT + (size_t)H_SZ * C_SZ * DK;
  __hip_bfloat16* WvT = WkT + (size_t)H_SZ * C_SZ * DK;

  w3_transpose_kernel<<<dim3(2, 2, 96), 256, 0, stream>>>(Wq, Wk, Wv, WqT, WkT, WvT);
  wo_transpose_kernel<<<dim3(64, 64), 256, 0, stream>>>(Wo, WoT);
  attn_kernel<<<dim3(H_SZ, B_SZ), 256, 0, stream>>>(Q, K, V, WqT, bq, WkT, bk, WvT, bv, Oc);
  out_gemm_kernel<<<dim3(13 * 16), 512, 0, stream>>>(Oc, WoT, bo, out);
}

// Round 8
// 207.273 us; speedup vs baseline: 1.1455x; 1.1455x over previous
//
#include <hip/hip_runtime.h>
#include <hip/hip_bf16.h>

// Problem constants
#define B_SZ   64
#define L_SZ   52
#define DMODEL 4096
#define H_SZ   32
#define C_SZ   128   // NEW_C = DMODEL/H
#define DK     128   // D_K == D_V

// Output GEMM dims: (B*L) x DMODEL = 3328 x 4096, K = 4096
#define GM 3328
#define GN 4096
#define GK 4096

typedef __bf16 bf16x8 __attribute__((ext_vector_type(8)));
typedef float  f32x4  __attribute__((ext_vector_type(4)));

__device__ __forceinline__ void gload_lds16(const void* g, void* l) {
  __builtin_amdgcn_global_load_lds(
      (__attribute__((address_space(1))) void*)(void*)g,
      (__attribute__((address_space(3))) void*)l, 16, 0, 0);
}

__device__ __forceinline__ unsigned short bfbits(float x) {
  union { __hip_bfloat16 h; unsigned short u; } c;
  c.h = __float2bfloat16(x);
  return c.u;
}

// ---------------------------------------------------------------------------
// Kernel 1a: Wo (4096x4096 fp32 [m][n]) -> WoT (4096x4096 bf16 [n][m])
// ---------------------------------------------------------------------------
__global__ __launch_bounds__(256) void wo_transpose_kernel(
    const float* __restrict__ Wo, __hip_bfloat16* __restrict__ WoT) {
  __shared__ float tile[64][65];
  const int nt = blockIdx.x, mt = blockIdx.y;
  const int t = threadIdx.x;
  const int r  = t >> 4;
  const int c4 = (t & 15) << 2;
#pragma unroll
  for (int p = 0; p < 4; ++p) {
    const int rr = r + p * 16;
    const float4 v = *(const float4*)(Wo + (size_t)(mt * 64 + rr) * 4096 + nt * 64 + c4);
    tile[rr][c4 + 0] = v.x; tile[rr][c4 + 1] = v.y;
    tile[rr][c4 + 2] = v.z; tile[rr][c4 + 3] = v.w;
  }
  __syncthreads();
#pragma unroll
  for (int p = 0; p < 4; ++p) {
    const int rr = r + p * 16;
    union { __hip_bfloat16 h[4]; ushort4 u; } o4;
#pragma unroll
    for (int e = 0; e < 4; ++e) o4.h[e] = __float2bfloat16(tile[c4 + e][rr]);
    *(ushort4*)(WoT + (size_t)(nt * 64 + rr) * 4096 + mt * 64 + c4) = o4.u;
  }
}

// ---------------------------------------------------------------------------
// Kernel 1b: Wq/Wk/Wv [h][c][k] fp32 -> [h][k][c] bf16   (batched 128x128 T)
// ---------------------------------------------------------------------------
__global__ __launch_bounds__(256) void w3_transpose_kernel(
    const float* __restrict__ Wq, const float* __restrict__ Wk,
    const float* __restrict__ Wv, __hip_bfloat16* __restrict__ WqT,
    __hip_bfloat16* __restrict__ WkT, __hip_bfloat16* __restrict__ WvT) {
  __shared__ float tile[64][65];
  const int bz = blockIdx.z;
  const float* in = (bz < 32 ? Wq : (bz < 64 ? Wk : Wv)) + (size_t)(bz & 31) * 16384;
  __hip_bfloat16* out = (bz < 32 ? WqT : (bz < 64 ? WkT : WvT)) + (size_t)(bz & 31) * 16384;
  const int nt = blockIdx.x, mt = blockIdx.y;  // 0..1
  const int t = threadIdx.x;
  const int r  = t >> 4;
  const int c4 = (t & 15) << 2;
#pragma unroll
  for (int p = 0; p < 4; ++p) {
    const int rr = r + p * 16;
    const float4 v = *(const float4*)(in + (size_t)(mt * 64 + rr) * 128 + nt * 64 + c4);
    tile[rr][c4 + 0] = v.x; tile[rr][c4 + 1] = v.y;
    tile[rr][c4 + 2] = v.z; tile[rr][c4 + 3] = v.w;
  }
  __syncthreads();
#pragma unroll
  for (int p = 0; p < 4; ++p) {
    const int rr = r + p * 16;
    union { __hip_bfloat16 h[4]; ushort4 u; } o4;
#pragma unroll
    for (int e = 0; e < 4; ++e) o4.h[e] = __float2bfloat16(tile[c4 + e][rr]);
    *(ushort4*)(out + (size_t)(nt * 64 + rr) * 128 + mt * 64 + c4) = o4.u;
  }
}

// ---------------------------------------------------------------------------
// Kernel 2: per-(b,h) MFMA attention. 256 thr = 4 waves; LDS 42432 B ->
// 3 blocks/CU (12 waves/CU). Three 14144 B regions (52 rows x 136 bf16,
// 272 B row stride = 2-way free bank aliasing). All MFMA fragment reads use
// row clamped to 51 (pad rows provably masked downstream). v never touches
// LDS: vproj result stays in registers; PV B-fragments are assembled by a
// fixed 64-bit shuffle permutation (src lane = 32*(kq&1)+r16 / +16,
// register m = 2*kk + (kq>>1)).
// Overlay chain: r0: xs_q -> k_sh -> p_sh ; r1: xs_k -> s_sh(f32,68) ;
// r2: xs_v -> q_sh.  Phases: stage B vproj B qproj B kproj B QK B SM B PV.
// ---------------------------------------------------------------------------
__device__ __forceinline__ void proj_lds(
    const __hip_bfloat16* __restrict__ xs, const __hip_bfloat16* __restrict__ WT,
    const float* __restrict__ bias, __hip_bfloat16* __restrict__ out,
    int n0, int r16, int kq) {
  f32x4 acc[4][2] = {};
  bf16x8 bfrag[2][4];
#pragma unroll
  for (int nt = 0; nt < 2; ++nt)
#pragma unroll
    for (int kk = 0; kk < 4; ++kk)
      bfrag[nt][kk] = *(const bf16x8*)(WT + (n0 + nt * 16 + r16) * 128 + kk * 32 + kq * 8);
#pragma unroll
  for (int kk = 0; kk < 4; ++kk) {
    bf16x8 a[4];
#pragma unroll
    for (int mt = 0; mt < 4; ++mt) {
      const int row = mt * 16 + r16;
      const int rowc = row < 52 ? row : 51;          // clamp: masked downstream
      a[mt] = *(const bf16x8*)(xs + rowc * 136 + kk * 32 + kq * 8);
    }
#pragma unroll
    for (int mt = 0; mt < 4; ++mt)
#pragma unroll
      for (int nt = 0; nt < 2; ++nt)
        acc[mt][nt] = __builtin_amdgcn_mfma_f32_16x16x32_bf16(a[mt], bfrag[nt][kk], acc[mt][nt], 0, 0, 0);
  }
#pragma unroll
  for (int nt = 0; nt < 2; ++nt) {
    const int col = n0 + nt * 16 + r16;
    const float bv = bias[col];
#pragma unroll
    for (int mt = 0; mt < 4; ++mt) {
      const int m0 = mt * 16 + kq * 4;
      if (m0 < 52) {                                  // rows >= 52 not stored
#pragma unroll
        for (int i = 0; i < 4; ++i)
          if (m0 + i < 52)
            out[(m0 + i) * 136 + col] = __float2bfloat16(acc[mt][nt][i] + bv);
      }
    }
  }
}

__device__ __forceinline__ uint2 shfl64(uint2 v, int lane) {
  uint2 r;
  r.x = (unsigned)__shfl((int)v.x, lane);
  r.y = (unsigned)__shfl((int)v.y, lane);
  return r;
}

__global__ __launch_bounds__(256, 3) void attn_kernel(
    const float* __restrict__ Qin, const float* __restrict__ Kin,
    const float* __restrict__ Vin,
    const __hip_bfloat16* __restrict__ WqT, const float* __restrict__ bq,
    const __hip_bfloat16* __restrict__ WkT, const float* __restrict__ bk,
    const __hip_bfloat16* __restrict__ WvT, const float* __restrict__ bv,
    __hip_bfloat16* __restrict__ Oc) {
  __shared__ __align__(16) char lds[42432];
  __hip_bfloat16* r0 = (__hip_bfloat16*)(lds);           // xs_q -> k_sh -> p_sh
  __hip_bfloat16* r1 = (__hip_bfloat16*)(lds + 14144);   // xs_k -> s_sh
  __hip_bfloat16* r2 = (__hip_bfloat16*)(lds + 28288);   // xs_v -> q_sh
  float*          s_sh = (float*)(lds + 14144);          // 52 x 68 f32
  __hip_bfloat16* p_sh = r0;                             // 52 x 72 bf16

  const int h = blockIdx.x, bb = blockIdx.y;
  const int t = threadIdx.x;
  const int w = t >> 6, lane = t & 63;
  const int r16 = lane & 15, kq = lane >> 4;
  const size_t xoff = (size_t)bb * (L_SZ * DMODEL) + (size_t)h * (L_SZ * C_SZ);
  const int n0 = w * 32;

  // ---- P0: stage X fp32 -> bf16 (52 rows only, stride 136) ----
  {
    const float* xp[3] = {Qin + xoff, Kin + xoff, Vin + xoff};
    __hip_bfloat16* xd[3] = {r0, r1, r2};
#pragma unroll
    for (int tz = 0; tz < 3; ++tz) {
      const float* X = xp[tz];
      __hip_bfloat16* xs = xd[tz];
      for (int idx = t; idx < 52 * 32; idx += 256) {
        const int row = idx >> 5, c4 = (idx & 31) << 2;
        const float4 v = *(const float4*)(X + row * 128 + c4);
        union { __hip_bfloat16 h[4]; ushort4 u; } o4;
        o4.h[0] = __float2bfloat16(v.x); o4.h[1] = __float2bfloat16(v.y);
        o4.h[2] = __float2bfloat16(v.z); o4.h[3] = __float2bfloat16(v.w);
        *(ushort4*)(xs + row * 136 + c4) = o4.u;
      }
    }
  }
  __syncthreads();   // B1

  // ---- P1: vproj -> registers (vb[m][nt] = rows kq*4..+3 packed bf16) ----
  uint2 vb[4][2];
  {
    f32x4 acc[4][2] = {};
    bf16x8 bfrag[2][4];
    const __hip_bfloat16* WT = WvT + (size_t)h * 16384;
#pragma unroll
    for (int nt = 0; nt < 2; ++nt)
#pragma unroll
      for (int kk = 0; kk < 4; ++kk)
        bfrag[nt][kk] = *(const bf16x8*)(WT + (n0 + nt * 16 + r16) * 128 + kk * 32 + kq * 8);
#pragma unroll
    for (int kk = 0; kk < 4; ++kk) {
      bf16x8 a[4];
#pragma unroll
      for (int mt = 0; mt < 4; ++mt) {
        const int row = mt * 16 + r16;
        const int rowc = row < 52 ? row : 51;
        a[mt] = *(const bf16x8*)(r2 + rowc * 136 + kk * 32 + kq * 8);
      }
#pragma unroll
      for (int mt = 0; mt < 4; ++mt)
#pragma unroll
        for (int nt = 0; nt < 2; ++nt)
          acc[mt][nt] = __builtin_amdgcn_mfma_f32_16x16x32_bf16(a[mt], bfrag[nt][kk], acc[mt][nt], 0, 0, 0);
    }
#pragma unroll
    for (int nt = 0; nt < 2; ++nt) {
      const float bvv = bv[h * 128 + n0 + nt * 16 + r16];
#pragma unroll
      for (int mt = 0; mt < 4; ++mt) {
        vb[mt][nt].x = (unsigned)bfbits(acc[mt][nt][0] + bvv) |
                       ((unsigned)bfbits(acc[mt][nt][1] + bvv) << 16);
        vb[mt][nt].y = (unsigned)bfbits(acc[mt][nt][2] + bvv) |
                       ((unsigned)bfbits(acc[mt][nt][3] + bvv) << 16);
      }
    }
  }
  __syncthreads();   // B2 (vproj done reading r2 before qproj writes it)

  // ---- P2: qproj r0 -> r2 ----
  proj_lds(r0, WqT + (size_t)h * 16384, bq + h * 128, r2, n0, r16, kq);
  __syncthreads();   // B3

  // ---- P3: kproj r1 -> r0 ----
  proj_lds(r1, WkT + (size_t)h * 16384, bk + h * 128, r0, n0, r16, kq);
  __syncthreads();   // B4

  // ---- P4: QK^T: q(r2) x k(r0) -> s_sh(r1), scaled, rows<52 ----
  {
    const int nq = w * 16;
    f32x4 sacc[4] = {};
#pragma unroll
    for (int kk = 0; kk < 4; ++kk) {
      const int krow = nq + r16;
      const int krc = krow < 52 ? krow : 51;
      const bf16x8 bf_ = *(const bf16x8*)(r0 + krc * 136 + kk * 32 + kq * 8);
#pragma unroll
      for (int mt = 0; mt < 4; ++mt) {
        const int qrow = mt * 16 + r16;
        const int qrc = qrow < 52 ? qrow : 51;
        const bf16x8 a = *(const bf16x8*)(r2 + qrc * 136 + kk * 32 + kq * 8);
        sacc[mt] = __builtin_amdgcn_mfma_f32_16x16x32_bf16(a, bf_, sacc[mt], 0, 0, 0);
      }
    }
    const float scale = 0.08838834764831845f;  // 1/sqrt(128)
#pragma unroll
    for (int mt = 0; mt < 4; ++mt)
#pragma unroll
      for (int i = 0; i < 4; ++i) {
        const int row = mt * 16 + kq * 4 + i;
        if (row < 52) s_sh[row * 68 + nq + r16] = sacc[mt][i] * scale;
      }
  }
  __syncthreads();   // B5

  // ---- P5: masked softmax s_sh(r1) -> p_sh(r0, stride 72, rows<52) ----
  {
    const int r = t >> 2, qd = t & 3;   // 4 lanes/row, 16 cols each
    if (r < 52) {
      float v[16];
      float mx = -3e38f;
#pragma unroll
      for (int j4 = 0; j4 < 4; ++j4) {
        const f32x4 s4 = *(const f32x4*)(s_sh + r * 68 + qd * 16 + j4 * 4);
#pragma unroll
        for (int e = 0; e < 4; ++e) {
          const int col = qd * 16 + j4 * 4 + e;
          const float val = (col <= r) ? s4[e] : -3e38f;
          v[j4 * 4 + e] = val;
          mx = fmaxf(mx, val);
        }
      }
      mx = fmaxf(mx, __shfl_xor(mx, 1));
      mx = fmaxf(mx, __shfl_xor(mx, 2));
      float ex[16];
      float sum = 0.f;
#pragma unroll
      for (int j = 0; j < 16; ++j) {
        const int col = qd * 16 + j;
        const float e = (col <= r) ? __expf(v[j] - mx) : 0.f;
        ex[j] = e; sum += e;
      }
      sum += __shfl_xor(sum, 1);
      sum += __shfl_xor(sum, 2);
      const float inv = 1.0f / sum;
      union { __hip_bfloat16 h[8]; uint4 q; } p0, p1;
#pragma unroll
      for (int j = 0; j < 8; ++j) {
        p0.h[j] = __float2bfloat16(ex[j] * inv);
        p1.h[j] = __float2bfloat16(ex[8 + j] * inv);
      }
      *(uint4*)(p_sh + r * 72 + qd * 16)     = p0.q;
      *(uint4*)(p_sh + r * 72 + qd * 16 + 8) = p1.q;
    }
  }
  __syncthreads();   // B6

  // ---- P6: PV: p(r0) x v(registers, shuffled) -> Oc ----
  {
    const int half = (kq >> 1) & 1;
    const int src0 = ((kq & 1) << 5) + r16;
    const int src1 = src0 + 16;
    f32x4 oacc[4][2] = {};
#pragma unroll
    for (int kk = 0; kk < 2; ++kk) {
      bf16x8 bfr[2];
#pragma unroll
      for (int nt = 0; nt < 2; ++nt) {
        const uint2 a0 = shfl64(vb[2 * kk + 0][nt], src0);
        const uint2 a1 = shfl64(vb[2 * kk + 1][nt], src0);
        const uint2 b0 = shfl64(vb[2 * kk + 0][nt], src1);
        const uint2 b1 = shfl64(vb[2 * kk + 1][nt], src1);
        union { unsigned u[4]; bf16x8 v; } asm_;
        asm_.u[0] = half ? a1.x : a0.x;
        asm_.u[1] = half ? a1.y : a0.y;
        asm_.u[2] = half ? b1.x : b0.x;
        asm_.u[3] = half ? b1.y : b0.y;
        bfr[nt] = asm_.v;
      }
#pragma unroll
      for (int mt = 0; mt < 4; ++mt) {
        const int prow = mt * 16 + r16;
        const int prc = prow < 52 ? prow : 51;
        const bf16x8 a = *(const bf16x8*)(p_sh + prc * 72 + kk * 32 + kq * 8);
#pragma unroll
        for (int nt = 0; nt < 2; ++nt)
          oacc[mt][nt] = __builtin_amdgcn_mfma_f32_16x16x32_bf16(a, bfr[nt], oacc[mt][nt], 0, 0, 0);
      }
    }
    const size_t obase = (size_t)bb * 52 * 4096 + (size_t)h * 128;
#pragma unroll
    for (int nt = 0; nt < 2; ++nt) {
      const int col = n0 + nt * 16 + r16;
#pragma unroll
      for (int mt = 0; mt < 4; ++mt) {
        const int row0 = mt * 16 + kq * 4;
#pragma unroll
        for (int i = 0; i < 4; ++i) {
          const int row = row0 + i;
          if (row < 52)
            Oc[obase + (size_t)row * 4096 + col] = __float2bfloat16(oacc[mt][nt][i]);
        }
      }
    }
  }
}

// ---------------------------------------------------------------------------
// Kernel 3: C = Oc @ WoT^T + bo — m201-style 4-phase/K-tile schedule (as R6).
// ---------------------------------------------------------------------------
#define STAGE(GBASE, REGOFF, KT, KS, WB) do {                                  \
    const __hip_bfloat16* s_ = (GBASE) + (size_t)(KT) * 64 + (KS) * 32;        \
    char* d_ = (WB) + (REGOFF) + ((KS) ? 16384 : 0) + t * 16;                  \
    gload_lds16(s_, d_);                                                       \
    gload_lds16(s_ + (size_t)128 * GK, d_ + 8192);                             \
  } while (0)

#define MFMA16(MQ, BF)                                                         \
  __builtin_amdgcn_sched_barrier(0);                                           \
  __builtin_amdgcn_s_setprio(1);                                               \
  _Pragma("unroll")                                                            \
  for (int mf = 0; mf < 4; ++mf)                                               \
    _Pragma("unroll")                                                          \
    for (int nf = 0; nf < 4; ++nf)                                             \
      acc[(MQ) * 4 + mf][nf] = __builtin_amdgcn_mfma_f32_16x16x32_bf16(        \
          af[mf], BF[nf], acc[(MQ) * 4 + mf][nf], 0, 0, 0);                    \
  __builtin_amdgcn_s_setprio(0)

#define READ_AF(KS, MQ)                                                        \
  _Pragma("unroll")                                                            \
  for (int mf = 0; mf < 4; ++mf)                                               \
    af[mf] = *(const bf16x8*)(rb + (KS) * 16384 + (MQ) * 4096 + aB0 + mf * 1024)

#define READ_BF(BF, KS)                                                        \
  _Pragma("unroll")                                                            \
  for (int nf = 0; nf < 4; ++nf)                                               \
    BF[nf] = *(const bf16x8*)(rb + 32768 + (KS) * 16384 + bB0 + nf * 1024)

__global__ __launch_bounds__(512, 2) void out_gemm_kernel(
    const __hip_bfloat16* __restrict__ A, const __hip_bfloat16* __restrict__ Bt,
    const float* __restrict__ bias, float* __restrict__ C) {
  __shared__ __align__(16) char lds[131072];   // 2 bufs x 64 KB

  int bid = blockIdx.x;
  bid = (bid & 7) * 26 + (bid >> 3);     // XCD swizzle, 208 % 8 == 0 (bijective)
  const int tm = bid >> 4;               // 0..12
  const int tn = bid & 15;               // 0..15

  const int t = threadIdx.x;
  const int w = t >> 6, lane = t & 63;
  const int wm = w >> 2, wn = w & 3;     // 2M x 4N waves; wave tile 128x64
  const int r16 = lane & 15, kq = lane >> 4;

  const int srow = t >> 2;
  const int sgslot = (t & 3) ^ ((srow >> 1) & 3);
  const __hip_bfloat16* gA0 = A  + (size_t)(tm * 256 + srow) * GK + sgslot * 8;
  const __hip_bfloat16* gB0 = Bt + (size_t)(tn * 256 + srow) * GK + sgslot * 8;

  const int slotr = kq ^ ((r16 >> 1) & 3);
  const int aB0 = (wm * 128 + r16) * 64 + slotr * 16;
  const int bB0 = (wn * 64 + r16) * 64 + slotr * 16;

  f32x4 acc[8][4] = {};
  bf16x8 bf0[4], bf1[4];

  STAGE(gA0, 0,     0, 0, lds);
  STAGE(gA0, 0,     0, 1, lds);
  STAGE(gB0, 32768, 0, 0, lds);
  STAGE(gB0, 32768, 0, 1, lds);
  STAGE(gB0, 32768, 1, 0, lds + 65536);
  STAGE(gA0, 0,     1, 0, lds + 65536);
  STAGE(gB0, 32768, 1, 1, lds + 65536);
  asm volatile("s_waitcnt vmcnt(6)" ::: "memory");   // T0's 8 loads landed
  __builtin_amdgcn_s_barrier();

#pragma unroll 1
  for (int kt = 0; kt < 64; ++kt) {
    char* rb = lds + ((kt & 1) << 16);
    char* ob = lds + (((kt + 1) & 1) << 16);
    const int s1 = kt + 1 < 64 ? kt + 1 : 63;
    const int s2 = kt + 2 < 64 ? kt + 2 : 63;

    {
      bf16x8 af[4];
      READ_AF(0, 0);
      READ_BF(bf0, 0);
      STAGE(gA0, 0, s1, 1, ob);
      __builtin_amdgcn_s_barrier();
      asm volatile("s_waitcnt lgkmcnt(0)" ::: "memory");
      MFMA16(0, bf0);
      __builtin_amdgcn_s_barrier();
    }
    {
      bf16x8 af[4];
      READ_AF(0, 1);
      STAGE(gB0, 32768, s2, 0, rb);
      __builtin_amdgcn_s_barrier();
      asm volatile("s_waitcnt lgkmcnt(0)" ::: "memory");
      MFMA16(1, bf0);
      __builtin_amdgcn_s_barrier();
    }
    {
      bf16x8 af[4];
      READ_AF(1, 0);
      READ_BF(bf1, 1);
      STAGE(gA0, 0, s2, 0, rb);
      __builtin_amdgcn_s_barrier();
      asm volatile("s_waitcnt lgkmcnt(0)" ::: "memory");
      MFMA16(0, bf1);
      __builtin_amdgcn_s_barrier();
    }
    {
      bf16x8 af[4];
      READ_AF(1, 1);
      STAGE(gB0, 32768, s2, 1, rb);
      __builtin_amdgcn_s_barrier();
      asm volatile("s_waitcnt lgkmcnt(0)" ::: "memory");
      MFMA16(1, bf1);
      asm volatile("s_waitcnt vmcnt(6)" ::: "memory");  // T+1 fully landed
      __builtin_amdgcn_s_barrier();
    }
  }
  asm volatile("s_waitcnt vmcnt(0) lgkmcnt(0)" ::: "memory");

  const int row0 = tm * 256 + wm * 128 + kq * 4;
  const int col0 = tn * 256 + wn * 64 + r16;
#pragma unroll
  for (int nf = 0; nf < 4; ++nf) {
    const int col = col0 + nf * 16;
    const float bv = bias[col];
#pragma unroll
    for (int mf = 0; mf < 8; ++mf) {
      const int row = row0 + mf * 16;
#pragma unroll
      for (int i = 0; i < 4; ++i)
        C[(size_t)(row + i) * GN + col] = acc[mf][nf][i] + bv;
    }
  }
}

// ---------------------------------------------------------------------------
extern "C" void kernel_launch(void* const* d_in, const int* in_sizes, int n_in,
                              void* d_out, int out_size, void* d_ws, size_t ws_size,
                              hipStream_t stream) {
  const float* Q  = (const float*)d_in[0];
  const float* K  = (const float*)d_in[1];
  const float* V  = (const float*)d_in[2];
  const float* Wq = (const float*)d_in[3];
  const float* bq = (const float*)d_in[4];
  const float* Wk = (const float*)d_in[5];
  const float* bk = (const float*)d_in[6];
  const float* Wv = (const float*)d_in[7];
  const float* bv = (const float*)d_in[8];
  const float* Wo = (const float*)d_in[9];
  const float* bo = (const float*)d_in[10];
  float* out = (float*)d_out;

  char* wsb = (char*)d_ws;
  __hip_bfloat16* WoT = (__hip_bfloat16*)wsb;
  __hip_bfloat16* Oc  = (__hip_bfloat16*)(wsb + (size_t)GN * GK * 2);
  __hip_bfloat16* WqT = (__hip_bfloat16*)(wsb + (size_t)GN * GK * 2 + (size_t)GM * GN * 2);
  __hip_bfloat16* WkT = WqT + (size_t)H_SZ * C_SZ * DK;
  __hip_bfloat16* WvT = WkT + (size_t)H_SZ * C_SZ * DK;

  w3_transpose_kernel<<<dim3(2, 2, 96), 256, 0, stream>>>(Wq, Wk, Wv, WqT, WkT, WvT);
  wo_transpose_kernel<<<dim3(64, 64), 256, 0, stream>>>(Wo, WoT);
  attn_kernel<<<dim3(H_SZ, B_SZ), 256, 0, stream>>>(Q, K, V, WqT, bq, WkT, bk, WvT, bv, Oc);
  out_gemm_kernel<<<dim3(13 * 16), 512, 0, stream>>>(Oc, WoT, bo, out);
}

// Round 9
// 192.403 us; speedup vs baseline: 1.2340x; 1.0773x over previous
//
#include <hip/hip_runtime.h>
#include <hip/hip_bf16.h>

// Problem constants
#define B_SZ   64
#define L_SZ   52
#define DMODEL 4096
#define H_SZ   32
#define C_SZ   128   // NEW_C = DMODEL/H
#define DK     128   // D_K == D_V

// Output GEMM dims: (B*L) x DMODEL = 3328 x 4096, K = 4096
#define GM 3328
#define GN 4096
#define GK 4096

typedef __bf16 bf16x8 __attribute__((ext_vector_type(8)));
typedef float  f32x4  __attribute__((ext_vector_type(4)));

__device__ __forceinline__ void gload_lds16(const void* g, void* l) {
  __builtin_amdgcn_global_load_lds(
      (__attribute__((address_space(1))) void*)(void*)g,
      (__attribute__((address_space(3))) void*)l, 16, 0, 0);
}

__device__ __forceinline__ unsigned short bfbits(float x) {
  union { __hip_bfloat16 h; unsigned short u; } c;
  c.h = __float2bfloat16(x);
  return c.u;
}

// ---------------------------------------------------------------------------
// Kernel 1b: Wq/Wk/Wv [h][c][k] fp32 -> [h][k][c] bf16   (batched 128x128 T)
// (stays separate: the fused attn kernel READS its outputs)
// ---------------------------------------------------------------------------
__global__ __launch_bounds__(256) void w3_transpose_kernel(
    const float* __restrict__ Wq, const float* __restrict__ Wk,
    const float* __restrict__ Wv, __hip_bfloat16* __restrict__ WqT,
    __hip_bfloat16* __restrict__ WkT, __hip_bfloat16* __restrict__ WvT) {
  __shared__ float tile[64][65];
  const int bz = blockIdx.z;
  const float* in = (bz < 32 ? Wq : (bz < 64 ? Wk : Wv)) + (size_t)(bz & 31) * 16384;
  __hip_bfloat16* out = (bz < 32 ? WqT : (bz < 64 ? WkT : WvT)) + (size_t)(bz & 31) * 16384;
  const int nt = blockIdx.x, mt = blockIdx.y;  // 0..1
  const int t = threadIdx.x;
  const int r  = t >> 4;
  const int c4 = (t & 15) << 2;
#pragma unroll
  for (int p = 0; p < 4; ++p) {
    const int rr = r + p * 16;
    const float4 v = *(const float4*)(in + (size_t)(mt * 64 + rr) * 128 + nt * 64 + c4);
    tile[rr][c4 + 0] = v.x; tile[rr][c4 + 1] = v.y;
    tile[rr][c4 + 2] = v.z; tile[rr][c4 + 3] = v.w;
  }
  __syncthreads();
#pragma unroll
  for (int p = 0; p < 4; ++p) {
    const int rr = r + p * 16;
    union { __hip_bfloat16 h[4]; ushort4 u; } o4;
#pragma unroll
    for (int e = 0; e < 4; ++e) o4.h[e] = __float2bfloat16(tile[c4 + e][rr]);
    *(ushort4*)(out + (size_t)(nt * 64 + rr) * 128 + mt * 64 + c4) = o4.u;
  }
}

// ---------------------------------------------------------------------------
// Kernel 2 (FUSED): blocks [0,2048) = per-(b,h) MFMA attention (as R8);
// blocks [2048,6144) = Wo fp32 [m][n] -> WoT bf16 [n][m] 64x64 transpose
// tiles. Disjoint data; WoT consumed only by the later GEMM kernel.
// Mechanism: transpose blocks (HBM-streaming) backfill CUs while
// latency-bound attn blocks stall, absorbing the former 19 us serial pass.
// ---------------------------------------------------------------------------
__device__ __forceinline__ void proj_lds(
    const __hip_bfloat16* __restrict__ xs, const __hip_bfloat16* __restrict__ WT,
    const float* __restrict__ bias, __hip_bfloat16* __restrict__ out,
    int n0, int r16, int kq) {
  f32x4 acc[4][2] = {};
  bf16x8 bfrag[2][4];
#pragma unroll
  for (int nt = 0; nt < 2; ++nt)
#pragma unroll
    for (int kk = 0; kk < 4; ++kk)
      bfrag[nt][kk] = *(const bf16x8*)(WT + (n0 + nt * 16 + r16) * 128 + kk * 32 + kq * 8);
#pragma unroll
  for (int kk = 0; kk < 4; ++kk) {
    bf16x8 a[4];
#pragma unroll
    for (int mt = 0; mt < 4; ++mt) {
      const int row = mt * 16 + r16;
      const int rowc = row < 52 ? row : 51;          // clamp: masked downstream
      a[mt] = *(const bf16x8*)(xs + rowc * 136 + kk * 32 + kq * 8);
    }
#pragma unroll
    for (int mt = 0; mt < 4; ++mt)
#pragma unroll
      for (int nt = 0; nt < 2; ++nt)
        acc[mt][nt] = __builtin_amdgcn_mfma_f32_16x16x32_bf16(a[mt], bfrag[nt][kk], acc[mt][nt], 0, 0, 0);
  }
#pragma unroll
  for (int nt = 0; nt < 2; ++nt) {
    const int col = n0 + nt * 16 + r16;
    const float bv = bias[col];
#pragma unroll
    for (int mt = 0; mt < 4; ++mt) {
      const int m0 = mt * 16 + kq * 4;
      if (m0 < 52) {
#pragma unroll
        for (int i = 0; i < 4; ++i)
          if (m0 + i < 52)
            out[(m0 + i) * 136 + col] = __float2bfloat16(acc[mt][nt][i] + bv);
      }
    }
  }
}

__device__ __forceinline__ uint2 shfl64(uint2 v, int lane) {
  uint2 r;
  r.x = (unsigned)__shfl((int)v.x, lane);
  r.y = (unsigned)__shfl((int)v.y, lane);
  return r;
}

__global__ __launch_bounds__(256, 3) void attn_fused_kernel(
    const float* __restrict__ Qin, const float* __restrict__ Kin,
    const float* __restrict__ Vin,
    const __hip_bfloat16* __restrict__ WqT, const float* __restrict__ bq,
    const __hip_bfloat16* __restrict__ WkT, const float* __restrict__ bk,
    const __hip_bfloat16* __restrict__ WvT, const float* __restrict__ bv,
    __hip_bfloat16* __restrict__ Oc,
    const float* __restrict__ Wo, __hip_bfloat16* __restrict__ WoT) {
  __shared__ __align__(16) char lds[42432];
  const int gid = blockIdx.x;
  const int t = threadIdx.x;

  if (gid >= 2048) {
    // ---------------- Wo transpose tile (64x64) ----------------
    float* tile = (float*)lds;                     // [64][65] = 16640 B
    const int bid2 = gid - 2048;
    const int nt = bid2 & 63, mt = bid2 >> 6;
    const int r  = t >> 4;
    const int c4 = (t & 15) << 2;
#pragma unroll
    for (int p = 0; p < 4; ++p) {
      const int rr = r + p * 16;
      const float4 v = *(const float4*)(Wo + (size_t)(mt * 64 + rr) * 4096 + nt * 64 + c4);
      tile[rr * 65 + c4 + 0] = v.x; tile[rr * 65 + c4 + 1] = v.y;
      tile[rr * 65 + c4 + 2] = v.z; tile[rr * 65 + c4 + 3] = v.w;
    }
    __syncthreads();
#pragma unroll
    for (int p = 0; p < 4; ++p) {
      const int rr = r + p * 16;
      union { __hip_bfloat16 h[4]; ushort4 u; } o4;
#pragma unroll
      for (int e = 0; e < 4; ++e) o4.h[e] = __float2bfloat16(tile[(c4 + e) * 65 + rr]);
      *(ushort4*)(WoT + (size_t)(nt * 64 + rr) * 4096 + mt * 64 + c4) = o4.u;
    }
    return;
  }

  // ---------------- attention block (as R8) ----------------
  __hip_bfloat16* r0 = (__hip_bfloat16*)(lds);           // xs_q -> k_sh -> p_sh
  __hip_bfloat16* r1 = (__hip_bfloat16*)(lds + 14144);   // xs_k -> s_sh
  __hip_bfloat16* r2 = (__hip_bfloat16*)(lds + 28288);   // xs_v -> q_sh
  float*          s_sh = (float*)(lds + 14144);          // 52 x 68 f32
  __hip_bfloat16* p_sh = r0;                             // 52 x 72 bf16

  const int h = gid & 31, bb = gid >> 5;
  const int lane = t & 63;
  const int w = t >> 6;
  const int r16 = lane & 15, kq = lane >> 4;
  const size_t xoff = (size_t)bb * (L_SZ * DMODEL) + (size_t)h * (L_SZ * C_SZ);
  const int n0 = w * 32;

  // ---- P0: stage X fp32 -> bf16 (52 rows, stride 136) ----
  {
    const float* xp[3] = {Qin + xoff, Kin + xoff, Vin + xoff};
    __hip_bfloat16* xd[3] = {r0, r1, r2};
#pragma unroll
    for (int tz = 0; tz < 3; ++tz) {
      const float* X = xp[tz];
      __hip_bfloat16* xs = xd[tz];
      for (int idx = t; idx < 52 * 32; idx += 256) {
        const int row = idx >> 5, c4 = (idx & 31) << 2;
        const float4 v = *(const float4*)(X + row * 128 + c4);
        union { __hip_bfloat16 h[4]; ushort4 u; } o4;
        o4.h[0] = __float2bfloat16(v.x); o4.h[1] = __float2bfloat16(v.y);
        o4.h[2] = __float2bfloat16(v.z); o4.h[3] = __float2bfloat16(v.w);
        *(ushort4*)(xs + row * 136 + c4) = o4.u;
      }
    }
  }
  __syncthreads();   // B1

  // ---- P1: vproj -> registers ----
  uint2 vb[4][2];
  {
    f32x4 acc[4][2] = {};
    bf16x8 bfrag[2][4];
    const __hip_bfloat16* WT = WvT + (size_t)h * 16384;
#pragma unroll
    for (int nt = 0; nt < 2; ++nt)
#pragma unroll
      for (int kk = 0; kk < 4; ++kk)
        bfrag[nt][kk] = *(const bf16x8*)(WT + (n0 + nt * 16 + r16) * 128 + kk * 32 + kq * 8);
#pragma unroll
    for (int kk = 0; kk < 4; ++kk) {
      bf16x8 a[4];
#pragma unroll
      for (int mt = 0; mt < 4; ++mt) {
        const int row = mt * 16 + r16;
        const int rowc = row < 52 ? row : 51;
        a[mt] = *(const bf16x8*)(r2 + rowc * 136 + kk * 32 + kq * 8);
      }
#pragma unroll
      for (int mt = 0; mt < 4; ++mt)
#pragma unroll
        for (int nt = 0; nt < 2; ++nt)
          acc[mt][nt] = __builtin_amdgcn_mfma_f32_16x16x32_bf16(a[mt], bfrag[nt][kk], acc[mt][nt], 0, 0, 0);
    }
#pragma unroll
    for (int nt = 0; nt < 2; ++nt) {
      const float bvv = bv[h * 128 + n0 + nt * 16 + r16];
#pragma unroll
      for (int mt = 0; mt < 4; ++mt) {
        vb[mt][nt].x = (unsigned)bfbits(acc[mt][nt][0] + bvv) |
                       ((unsigned)bfbits(acc[mt][nt][1] + bvv) << 16);
        vb[mt][nt].y = (unsigned)bfbits(acc[mt][nt][2] + bvv) |
                       ((unsigned)bfbits(acc[mt][nt][3] + bvv) << 16);
      }
    }
  }
  __syncthreads();   // B2

  // ---- P2: qproj r0 -> r2 ----
  proj_lds(r0, WqT + (size_t)h * 16384, bq + h * 128, r2, n0, r16, kq);
  __syncthreads();   // B3

  // ---- P3: kproj r1 -> r0 ----
  proj_lds(r1, WkT + (size_t)h * 16384, bk + h * 128, r0, n0, r16, kq);
  __syncthreads();   // B4

  // ---- P4: QK^T: q(r2) x k(r0) -> s_sh(r1) ----
  {
    const int nq = w * 16;
    f32x4 sacc[4] = {};
#pragma unroll
    for (int kk = 0; kk < 4; ++kk) {
      const int krow = nq + r16;
      const int krc = krow < 52 ? krow : 51;
      const bf16x8 bf_ = *(const bf16x8*)(r0 + krc * 136 + kk * 32 + kq * 8);
#pragma unroll
      for (int mt = 0; mt < 4; ++mt) {
        const int qrow = mt * 16 + r16;
        const int qrc = qrow < 52 ? qrow : 51;
        const bf16x8 a = *(const bf16x8*)(r2 + qrc * 136 + kk * 32 + kq * 8);
        sacc[mt] = __builtin_amdgcn_mfma_f32_16x16x32_bf16(a, bf_, sacc[mt], 0, 0, 0);
      }
    }
    const float scale = 0.08838834764831845f;  // 1/sqrt(128)
#pragma unroll
    for (int mt = 0; mt < 4; ++mt)
#pragma unroll
      for (int i = 0; i < 4; ++i) {
        const int row = mt * 16 + kq * 4 + i;
        if (row < 52) s_sh[row * 68 + nq + r16] = sacc[mt][i] * scale;
      }
  }
  __syncthreads();   // B5

  // ---- P5: masked softmax s_sh(r1) -> p_sh(r0) ----
  {
    const int r = t >> 2, qd = t & 3;
    if (r < 52) {
      float v[16];
      float mx = -3e38f;
#pragma unroll
      for (int j4 = 0; j4 < 4; ++j4) {
        const f32x4 s4 = *(const f32x4*)(s_sh + r * 68 + qd * 16 + j4 * 4);
#pragma unroll
        for (int e = 0; e < 4; ++e) {
          const int col = qd * 16 + j4 * 4 + e;
          const float val = (col <= r) ? s4[e] : -3e38f;
          v[j4 * 4 + e] = val;
          mx = fmaxf(mx, val);
        }
      }
      mx = fmaxf(mx, __shfl_xor(mx, 1));
      mx = fmaxf(mx, __shfl_xor(mx, 2));
      float ex[16];
      float sum = 0.f;
#pragma unroll
      for (int j = 0; j < 16; ++j) {
        const int col = qd * 16 + j;
        const float e = (col <= r) ? __expf(v[j] - mx) : 0.f;
        ex[j] = e; sum += e;
      }
      sum += __shfl_xor(sum, 1);
      sum += __shfl_xor(sum, 2);
      const float inv = 1.0f / sum;
      union { __hip_bfloat16 h[8]; uint4 q; } p0, p1;
#pragma unroll
      for (int j = 0; j < 8; ++j) {
        p0.h[j] = __float2bfloat16(ex[j] * inv);
        p1.h[j] = __float2bfloat16(ex[8 + j] * inv);
      }
      *(uint4*)(p_sh + r * 72 + qd * 16)     = p0.q;
      *(uint4*)(p_sh + r * 72 + qd * 16 + 8) = p1.q;
    }
  }
  __syncthreads();   // B6

  // ---- P6: PV: p(r0) x v(registers, shuffled) -> Oc ----
  {
    const int half = (kq >> 1) & 1;
    const int src0 = ((kq & 1) << 5) + r16;
    const int src1 = src0 + 16;
    f32x4 oacc[4][2] = {};
#pragma unroll
    for (int kk = 0; kk < 2; ++kk) {
      bf16x8 bfr[2];
#pragma unroll
      for (int nt = 0; nt < 2; ++nt) {
        const uint2 a0 = shfl64(vb[2 * kk + 0][nt], src0);
        const uint2 a1 = shfl64(vb[2 * kk + 1][nt], src0);
        const uint2 b0 = shfl64(vb[2 * kk + 0][nt], src1);
        const uint2 b1 = shfl64(vb[2 * kk + 1][nt], src1);
        union { unsigned u[4]; bf16x8 v; } asm_;
        asm_.u[0] = half ? a1.x : a0.x;
        asm_.u[1] = half ? a1.y : a0.y;
        asm_.u[2] = half ? b1.x : b0.x;
        asm_.u[3] = half ? b1.y : b0.y;
        bfr[nt] = asm_.v;
      }
#pragma unroll
      for (int mt = 0; mt < 4; ++mt) {
        const int prow = mt * 16 + r16;
        const int prc = prow < 52 ? prow : 51;
        const bf16x8 a = *(const bf16x8*)(p_sh + prc * 72 + kk * 32 + kq * 8);
#pragma unroll
        for (int nt = 0; nt < 2; ++nt)
          oacc[mt][nt] = __builtin_amdgcn_mfma_f32_16x16x32_bf16(a, bfr[nt], oacc[mt][nt], 0, 0, 0);
      }
    }
    const size_t obase = (size_t)bb * 52 * 4096 + (size_t)h * 128;
#pragma unroll
    for (int nt = 0; nt < 2; ++nt) {
      const int col = n0 + nt * 16 + r16;
#pragma unroll
      for (int mt = 0; mt < 4; ++mt) {
        const int row0 = mt * 16 + kq * 4;
#pragma unroll
        for (int i = 0; i < 4; ++i) {
          const int row = row0 + i;
          if (row < 52)
            Oc[obase + (size_t)row * 4096 + col] = __float2bfloat16(oacc[mt][nt][i]);
        }
      }
    }
  }
}

// ---------------------------------------------------------------------------
// Kernel 3: C = Oc @ WoT^T + bo — m201-style 4-phase/K-tile schedule (R6),
// K-loop unrolled x2 so LDS buffer pointers are compile-time constants.
// ---------------------------------------------------------------------------
#define STAGE(GBASE, REGOFF, KT, KS, WB) do {                                  \
    const __hip_bfloat16* s_ = (GBASE) + (size_t)(KT) * 64 + (KS) * 32;        \
    char* d_ = (WB) + (REGOFF) + ((KS) ? 16384 : 0) + t * 16;                  \
    gload_lds16(s_, d_);                                                       \
    gload_lds16(s_ + (size_t)128 * GK, d_ + 8192);                             \
  } while (0)

#define MFMA16(MQ, BF)                                                         \
  __builtin_amdgcn_sched_barrier(0);                                           \
  __builtin_amdgcn_s_setprio(1);                                               \
  _Pragma("unroll")                                                            \
  for (int mf = 0; mf < 4; ++mf)                                               \
    _Pragma("unroll")                                                          \
    for (int nf = 0; nf < 4; ++nf)                                             \
      acc[(MQ) * 4 + mf][nf] = __builtin_amdgcn_mfma_f32_16x16x32_bf16(        \
          af[mf], BF[nf], acc[(MQ) * 4 + mf][nf], 0, 0, 0);                    \
  __builtin_amdgcn_s_setprio(0)

#define READ_AF(RB, KS, MQ)                                                    \
  _Pragma("unroll")                                                            \
  for (int mf = 0; mf < 4; ++mf)                                               \
    af[mf] = *(const bf16x8*)((RB) + (KS) * 16384 + (MQ) * 4096 + aB0 + mf * 1024)

#define READ_BF(RB, BF, KS)                                                    \
  _Pragma("unroll")                                                            \
  for (int nf = 0; nf < 4; ++nf)                                               \
    BF[nf] = *(const bf16x8*)((RB) + 32768 + (KS) * 16384 + bB0 + nf * 1024)

// one K-tile: 4 phases. RB = read buf (tile KT), OB = other buf.
#define KTILE_BODY(KT, RB, OB) do {                                            \
    const int s1 = (KT) + 1 < 64 ? (KT) + 1 : 63;                              \
    const int s2 = (KT) + 2 < 64 ? (KT) + 2 : 63;                              \
    {                                                                          \
      bf16x8 af[4];                                                            \
      READ_AF(RB, 0, 0);                                                       \
      READ_BF(RB, bf0, 0);                                                     \
      STAGE(gA0, 0, s1, 1, OB);                                                \
      __builtin_amdgcn_s_barrier();                                            \
      asm volatile("s_waitcnt lgkmcnt(0)" ::: "memory");                       \
      MFMA16(0, bf0);                                                          \
      __builtin_amdgcn_s_barrier();                                            \
    }                                                                          \
    {                                                                          \
      bf16x8 af[4];                                                            \
      READ_AF(RB, 0, 1);                                                       \
      STAGE(gB0, 32768, s2, 0, RB);                                            \
      __builtin_amdgcn_s_barrier();                                            \
      asm volatile("s_waitcnt lgkmcnt(0)" ::: "memory");                       \
      MFMA16(1, bf0);                                                          \
      __builtin_amdgcn_s_barrier();                                            \
    }                                                                          \
    {                                                                          \
      bf16x8 af[4];                                                            \
      READ_AF(RB, 1, 0);                                                       \
      READ_BF(RB, bf1, 1);                                                     \
      STAGE(gA0, 0, s2, 0, RB);                                                \
      __builtin_amdgcn_s_barrier();                                            \
      asm volatile("s_waitcnt lgkmcnt(0)" ::: "memory");                       \
      MFMA16(0, bf1);                                                          \
      __builtin_amdgcn_s_barrier();                                            \
    }                                                                          \
    {                                                                          \
      bf16x8 af[4];                                                            \
      READ_AF(RB, 1, 1);                                                       \
      STAGE(gB0, 32768, s2, 1, RB);                                            \
      __builtin_amdgcn_s_barrier();                                            \
      asm volatile("s_waitcnt lgkmcnt(0)" ::: "memory");                       \
      MFMA16(1, bf1);                                                          \
      asm volatile("s_waitcnt vmcnt(6)" ::: "memory");                         \
      __builtin_amdgcn_s_barrier();                                            \
    }                                                                          \
  } while (0)

__global__ __launch_bounds__(512, 2) void out_gemm_kernel(
    const __hip_bfloat16* __restrict__ A, const __hip_bfloat16* __restrict__ Bt,
    const float* __restrict__ bias, float* __restrict__ C) {
  __shared__ __align__(16) char lds[131072];   // 2 bufs x 64 KB

  int bid = blockIdx.x;
  bid = (bid & 7) * 26 + (bid >> 3);     // XCD swizzle, 208 % 8 == 0 (bijective)
  const int tm = bid >> 4;               // 0..12
  const int tn = bid & 15;               // 0..15

  const int t = threadIdx.x;
  const int w = t >> 6, lane = t & 63;
  const int wm = w >> 2, wn = w & 3;     // 2M x 4N waves; wave tile 128x64
  const int r16 = lane & 15, kq = lane >> 4;

  const int srow = t >> 2;
  const int sgslot = (t & 3) ^ ((srow >> 1) & 3);
  const __hip_bfloat16* gA0 = A  + (size_t)(tm * 256 + srow) * GK + sgslot * 8;
  const __hip_bfloat16* gB0 = Bt + (size_t)(tn * 256 + srow) * GK + sgslot * 8;

  const int slotr = kq ^ ((r16 >> 1) & 3);
  const int aB0 = (wm * 128 + r16) * 64 + slotr * 16;
  const int bB0 = (wn * 64 + r16) * 64 + slotr * 16;

  f32x4 acc[8][4] = {};
  bf16x8 bf0[4], bf1[4];

  char* const buf0 = lds;
  char* const buf1 = lds + 65536;

  // prologue: T0 all 4 regions -> buf0; T1 {B-ks0, A-ks0, B-ks1} -> buf1
  STAGE(gA0, 0,     0, 0, buf0);
  STAGE(gA0, 0,     0, 1, buf0);
  STAGE(gB0, 32768, 0, 0, buf0);
  STAGE(gB0, 32768, 0, 1, buf0);
  STAGE(gB0, 32768, 1, 0, buf1);
  STAGE(gA0, 0,     1, 0, buf1);
  STAGE(gB0, 32768, 1, 1, buf1);
  asm volatile("s_waitcnt vmcnt(6)" ::: "memory");   // T0's 8 loads landed
  __builtin_amdgcn_s_barrier();

#pragma unroll 1
  for (int kt2 = 0; kt2 < 32; ++kt2) {
    const int kt = kt2 * 2;
    KTILE_BODY(kt,     buf0, buf1);
    KTILE_BODY(kt + 1, buf1, buf0);
  }
  asm volatile("s_waitcnt vmcnt(0) lgkmcnt(0)" ::: "memory");

  const int row0 = tm * 256 + wm * 128 + kq * 4;
  const int col0 = tn * 256 + wn * 64 + r16;
#pragma unroll
  for (int nf = 0; nf < 4; ++nf) {
    const int col = col0 + nf * 16;
    const float bv = bias[col];
#pragma unroll
    for (int mf = 0; mf < 8; ++mf) {
      const int row = row0 + mf * 16;
#pragma unroll
      for (int i = 0; i < 4; ++i)
        C[(size_t)(row + i) * GN + col] = acc[mf][nf][i] + bv;
    }
  }
}

// ---------------------------------------------------------------------------
extern "C" void kernel_launch(void* const* d_in, const int* in_sizes, int n_in,
                              void* d_out, int out_size, void* d_ws, size_t ws_size,
                              hipStream_t stream) {
  const float* Q  = (const float*)d_in[0];
  const float* K  = (const float*)d_in[1];
  const float* V  = (const float*)d_in[2];
  const float* Wq = (const float*)d_in[3];
  const float* bq = (const float*)d_in[4];
  const float* Wk = (const float*)d_in[5];
  const float* bk = (const float*)d_in[6];
  const float* Wv = (const float*)d_in[7];
  const float* bv = (const float*)d_in[8];
  const float* Wo = (const float*)d_in[9];
  const float* bo = (const float*)d_in[10];
  float* out = (float*)d_out;

  char* wsb = (char*)d_ws;
  __hip_bfloat16* WoT = (__hip_bfloat16*)wsb;
  __hip_bfloat16* Oc  = (__hip_bfloat16*)(wsb + (size_t)GN * GK * 2);
  __hip_bfloat16* WqT = (__hip_bfloat16*)(wsb + (size_t)GN * GK * 2 + (size_t)GM * GN * 2);
  __hip_bfloat16* WkT = WqT + (size_t)H_SZ * C_SZ * DK;
  __hip_bfloat16* WvT = WkT + (size_t)H_SZ * C_SZ * DK;

  w3_transpose_kernel<<<dim3(2, 2, 96), 256, 0, stream>>>(Wq, Wk, Wv, WqT, WkT, WvT);
  attn_fused_kernel<<<dim3(2048 + 4096), 256, 0, stream>>>(
      Q, K, V, WqT, bq, WkT, bk, WvT, bv, Oc, Wo, WoT);
  out_gemm_kernel<<<dim3(13 * 16), 512, 0, stream>>>(Oc, WoT, bo, out);
}